// Round 16
// baseline (176.355 us; speedup 1.0000x reference)
//
#include <hip/hip_runtime.h>
#include <hip/hip_bf16.h>
#include <math.h>

#define NPTS 2048
#define BN   16384
#define KNN_K 32
typedef unsigned long long u64;
typedef float f32x4 __attribute__((ext_vector_type(4)));
#define INF64 0xFFFFFFFFFFFFFFFFull

__device__ __forceinline__ u64 umin64(u64 a, u64 b) { return a < b ? a : b; }

// ---------------- Kernel A: exact kNN via prune + bitonic sort ----------------
// NO LDS point staging (round-15 lesson: 96 ds_reads/query saturated the DS
// pipe at ~25 us/CU while VMEM idled). Points read from global: 24 KB batch
// slab is L1-resident, consecutive blocks share a batch. LDS = surv only (2KB).
// 4 queries/block, 256 threads, 4096 blocks. No launch_bounds cap (round-14
// lesson: caps below ~48 VGPR spill d[32] to scratch).
__global__ __launch_bounds__(256) void knn_kernel(const float* __restrict__ pts,
                                                  int* __restrict__ knn) {
    __shared__ u64 surv[4][64];                      // 2 KB
    const int b = blockIdx.x >> 9;                   // 512 blocks per batch
    const int qbase = (blockIdx.x & 511) << 2;       // 4 queries per block
    const float* pb = pts + (size_t)b * NPTS * 3;
    const int wave = threadIdx.x >> 6, lane = threadIdx.x & 63;
    const int q = qbase + wave;
    const float qx = pb[q * 3 + 0], qy = pb[q * 3 + 1], qz = pb[q * 3 + 2];

    // exact reference-order distances (no FMA contraction, correctly-rounded sqrt)
    float d[32];
#pragma unroll
    for (int t = 0; t < 32; ++t) {
        int j = t * 64 + lane;
        float x = pb[j * 3 + 0], y = pb[j * 3 + 1], z = pb[j * 3 + 2];
        float dx = __fsub_rn(qx, x);
        float dy = __fsub_rn(qy, y);
        float dz = __fsub_rn(qz, z);
        float d2 = __fadd_rn(__fadd_rn(__fmul_rn(dx, dx), __fmul_rn(dy, dy)),
                             __fmul_rn(dz, dz));
        d[t] = __fsqrt_rn(d2);
    }

    float lmin = d[0];
#pragma unroll
    for (int t = 1; t < 32; ++t) lmin = fminf(lmin, d[t]);

    // bitonic sort of 64 lane-minima
    float v = lmin;
#pragma unroll
    for (int k = 2; k <= 64; k <<= 1) {
#pragma unroll
        for (int j = k >> 1; j > 0; j >>= 1) {
            float o = __shfl_xor(v, j, 64);
            bool up = ((lane & k) == 0);
            bool low = ((lane & j) == 0);
            float mn = fminf(v, o), mx = fmaxf(v, o);
            v = (low == up) ? mn : mx;
        }
    }
    float Tpre = __shfl(v, 31, 64);   // >= 32nd-smallest global distance

    u64* sw = surv[wave];
    unsigned cnt = 0;
#pragma unroll
    for (int t = 0; t < 32; ++t) {
        bool sel = (d[t] <= Tpre);
        u64 m = __ballot(sel);
        if (sel) {
            u64 key = ((u64)__float_as_uint(d[t]) << 32) | (unsigned)(t * 64 + lane);
            unsigned pos = cnt + (unsigned)__popcll(m & ((1ull << lane) - 1ull));
            if (pos < 64) sw[pos] = key;
        }
        cnt += (unsigned)__popcll(m);
    }

    int* kout = knn + ((size_t)b * NPTS + q) * KNN_K;
    __asm__ volatile("s_waitcnt lgkmcnt(0)" ::: "memory");  // own-wave LDS W->R fence

    if (cnt <= 64) {
        u64 key = (lane < (int)cnt) ? sw[lane] : INF64;
#pragma unroll
        for (int k = 2; k <= 64; k <<= 1) {
#pragma unroll
            for (int j = k >> 1; j > 0; j >>= 1) {
                u64 o = __shfl_xor(key, j, 64);
                bool up = ((lane & k) == 0);
                bool low = ((lane & j) == 0);
                bool lt = key < o;
                u64 mn = lt ? key : o, mx = lt ? o : key;
                key = (low == up) ? mn : mx;
            }
        }
        if (lane < KNN_K) kout[lane] = (int)(unsigned)(key & 0xFFFFFFFFull);
    } else {
        // rare exact fallback (survivors > 64)
        unsigned fmask = 0xFFFFFFFFu;
        for (int r = 0; r < KNN_K; ++r) {
            u64 mm = INF64;
#pragma unroll
            for (int t = 0; t < 32; ++t) {
                u64 kk = ((u64)__float_as_uint(d[t]) << 32) | (unsigned)(t * 64 + lane);
                mm = umin64(mm, ((fmask >> t) & 1u) ? kk : INF64);
            }
#pragma unroll
            for (int s = 1; s < 64; s <<= 1) mm = umin64(mm, __shfl_xor(mm, s, 64));
            unsigned j = (unsigned)(mm & 0xFFFFFFFFull);
            if (lane == (int)(j & 63)) fmask &= ~(1u << (j >> 6));
            if (lane == 0) kout[r] = (int)j;
        }
    }
}

// ---------------- Kernel B: fused MLP (layers 1..3) -> f3 [BN][256] ----------------
// Pp=8: 512 blocks x 256 threads, 32 points/block, wave owns 8 points both
// phases (own-wave lgkmcnt fence, no __syncthreads). W3 L2 stream halves
// again vs Pp=4: 2.15 GB / Pp = 269 MB.
__global__ __launch_bounds__(256, 4) void mlp123_kernel(const float* __restrict__ pts,
        const float* __restrict__ W1, const float* __restrict__ b1,
        const float* __restrict__ W2, const float* __restrict__ b2,
        const float* __restrict__ W3, const float* __restrict__ b3,
        float* __restrict__ f3) {
    __shared__ float h2s[32][128];   // 16 KB
    const int tid = threadIdx.x;
    const int wv = tid >> 6, lane = tid & 63;
    const int p0 = blockIdx.x << 5;
    const int pbase = wv * 8;        // this wave's local points

    // ---- phase 0: layers 1+2 for this wave's 8 points ----
    {
        const float w1a = W1[lane], w1b = W1[64 + lane], w1c = W1[128 + lane];
        const float b1v = b1[lane];
        float h1v[8];
#pragma unroll
        for (int p = 0; p < 8; ++p) {
            const int pp = __builtin_amdgcn_readfirstlane(p0 + pbase + p);
            const float* ptp = pts + (size_t)pp * 3;
            h1v[p] = fmaxf(fmaf(ptp[0], w1a, fmaf(ptp[1], w1b, fmaf(ptp[2], w1c, b1v))), 0.f);
        }
        float2 b2v = *(const float2*)(b2 + 2 * lane);
        float a0[8], a1[8];
#pragma unroll
        for (int p = 0; p < 8; ++p) { a0[p] = b2v.x; a1[p] = b2v.y; }
#pragma unroll 2
        for (int i = 0; i < 64; ++i) {
            float2 w = *(const float2*)(W2 + i * 128 + 2 * lane);
#pragma unroll
            for (int p = 0; p < 8; ++p) {
                float h = __shfl(h1v[p], i, 64);
                a0[p] = fmaf(h, w.x, a0[p]);
                a1[p] = fmaf(h, w.y, a1[p]);
            }
        }
#pragma unroll
        for (int p = 0; p < 8; ++p)
            *(float2*)&h2s[pbase + p][2 * lane] =
                make_float2(fmaxf(a0[p], 0.f), fmaxf(a1[p], 0.f));
    }
    // own-wave LDS write->read fence (phase 1 reads only this wave's rows)
    __asm__ volatile("s_waitcnt lgkmcnt(0)" ::: "memory");

    // ---- phase 1: layer 3; lane -> channels c0..c0+3, points pbase..pbase+7 ----
    const int c0 = lane * 4;
    float4 acc[8];
#pragma unroll
    for (int p = 0; p < 8; ++p) acc[p] = make_float4(0.f, 0.f, 0.f, 0.f);
    for (int k4 = 0; k4 < 32; ++k4) {
        float4 h[8];
#pragma unroll
        for (int p = 0; p < 8; ++p)
            h[p] = *(const float4*)&h2s[pbase + p][k4 * 4];
#pragma unroll
        for (int u = 0; u < 4; ++u) {
            float4 w = *(const float4*)(W3 + (size_t)(k4 * 4 + u) * 256 + c0);
#pragma unroll
            for (int p = 0; p < 8; ++p) {
                float e = (u == 0) ? h[p].x : (u == 1) ? h[p].y
                          : (u == 2) ? h[p].z : h[p].w;
                acc[p].x = fmaf(e, w.x, acc[p].x);
                acc[p].y = fmaf(e, w.y, acc[p].y);
                acc[p].z = fmaf(e, w.z, acc[p].z);
                acc[p].w = fmaf(e, w.w, acc[p].w);
            }
        }
    }
    float4 bb = *(const float4*)(b3 + c0);
#pragma unroll
    for (int p = 0; p < 8; ++p) {
        float4 r = make_float4(fmaxf(acc[p].x + bb.x, 0.f), fmaxf(acc[p].y + bb.y, 0.f),
                               fmaxf(acc[p].z + bb.z, 0.f), fmaxf(acc[p].w + bb.w, 0.f));
        *(float4*)(f3 + ((size_t)(p0 + pbase + p)) * 256 + c0) = r;
    }
}

// ---------------- Kernel C: gather + mean; batch pinned to XCD via blockIdx&7 ----------------
__global__ __launch_bounds__(256) void gather_mean_kernel(const float* __restrict__ f3,
        const int* __restrict__ knn, float* __restrict__ out) {
    int wave = threadIdx.x >> 6, lane = threadIdx.x & 63;
    int b  = blockIdx.x & 7;
    int qg = blockIdx.x >> 3;          // 0..511
    int q  = b * NPTS + qg * 4 + wave;
    // prefetch all 32 neighbor indices first (8 x int4, static component use)
    const int4* kq4 = (const int4*)(knn + (size_t)q * KNN_K);
    int4 kidx[8];
#pragma unroll
    for (int k8 = 0; k8 < 8; ++k8) kidx[k8] = kq4[k8];
    const float4* fb = (const float4*)(f3 + (size_t)b * NPTS * 256);
    float4 acc = make_float4(0.f, 0.f, 0.f, 0.f);
#pragma unroll
    for (int k8 = 0; k8 < 8; ++k8) {
        int4 kk = kidx[k8];
        float4 v0 = fb[(size_t)kk.x * 64 + lane];
        float4 v1 = fb[(size_t)kk.y * 64 + lane];
        float4 v2 = fb[(size_t)kk.z * 64 + lane];
        float4 v3 = fb[(size_t)kk.w * 64 + lane];
        acc.x += v0.x; acc.y += v0.y; acc.z += v0.z; acc.w += v0.w;
        acc.x += v1.x; acc.y += v1.y; acc.z += v1.z; acc.w += v1.w;
        acc.x += v2.x; acc.y += v2.y; acc.z += v2.z; acc.w += v2.w;
        acc.x += v3.x; acc.y += v3.y; acc.z += v3.z; acc.w += v3.w;
    }
    f32x4 r;
    r.x = acc.x * 0.03125f; r.y = acc.y * 0.03125f;
    r.z = acc.z * 0.03125f; r.w = acc.w * 0.03125f;
    __builtin_nontemporal_store(r, (f32x4*)(out + (size_t)q * 256 + lane * 4));
}

extern "C" void kernel_launch(void* const* d_in, const int* in_sizes, int n_in,
                              void* d_out, int out_size, void* d_ws, size_t ws_size,
                              hipStream_t stream) {
    const float* pts = (const float*)d_in[0];
    const float* W1  = (const float*)d_in[1];
    const float* b1  = (const float*)d_in[2];
    const float* W2  = (const float*)d_in[3];
    const float* b2  = (const float*)d_in[4];
    const float* W3  = (const float*)d_in[5];
    const float* b3  = (const float*)d_in[6];
    float* out = (float*)d_out;
    char* ws = (char*)d_ws;
    int*   knn = (int*)ws;                               // 2 MB
    float* f3  = (float*)(ws + ((size_t)2 << 20));       // 16.8 MB

    hipLaunchKernelGGL(knn_kernel,         dim3(4096), dim3(256), 0, stream, pts, knn);
    hipLaunchKernelGGL(mlp123_kernel,      dim3(512),  dim3(256), 0, stream,
                       pts, W1, b1, W2, b2, W3, b3, f3);
    hipLaunchKernelGGL(gather_mean_kernel, dim3(4096), dim3(256), 0, stream, f3, knn, out);
}